// Round 2
// baseline (1568535.352 us; speedup 1.0000x reference)
//
#include <hip/hip_runtime.h>
#include <math.h>

// ControlledNODE: sequential RK4 scan, T=65536 steps.
// SINGLE-WAVE version: 64 threads = 1 wave. No s_barrier anywhere --
// wave-synchronous LDS (DS ops from one wave execute in program order;
// __builtin_amdgcn_wave_barrier() is a free compile-time ordering fence).
// Thread j owns hidden units j and j+64; all weights live in VGPRs
// (gfx950 unified 512-reg file; weights = 400 VGPRs).
// Cross-half drift reduce via one shfl_xor(32). RK state replicated in
// both wave halves so the combine needs no extra sync.

constexpr int T_STEPS = 65536;
constexpr int HD  = 32;   // state dim
constexpr int HID = 128;  // hidden dim

__device__ __forceinline__ float silu_f(float a) {
    // a * sigmoid(a); exp overflow -> inf -> a/inf = 0 (correct limit)
    return a / (1.0f + __expf(-a));
}

__global__ __launch_bounds__(64, 1)
void node_scan(const float* __restrict__ U,
               const float* __restrict__ h0,
               const float* __restrict__ W1, const float* __restrict__ b1,
               const float* __restrict__ W2, const float* __restrict__ b2,
               const float* __restrict__ W3, const float* __restrict__ b3,
               const float* __restrict__ Wd, const float* __restrict__ bd,
               const float* __restrict__ Wt, const float* __restrict__ bt,
               const float* __restrict__ Wc, const float* __restrict__ bc,
               float* __restrict__ out)
{
    const int tid  = threadIdx.x;   // 0..63
    const int j    = tid;           // owns hidden units j and j+64
    const int m    = tid & 31;      // drift/state index
    const int half = tid >> 5;      // 0 or 1: L3 K-half, head selector

    __shared__ __align__(16) float xbuf[HD];    // current RK-stage state
    __shared__ __align__(16) float z1buf[HID];  // slot 2q = unit q, 2q+1 = unit q+64
    __shared__ __align__(16) float z2buf[HID];  // same slot layout

    // ---- one-time: weights into registers ----
    float w1x[40], w1y[40];
#pragma unroll
    for (int i = 0; i < 40; ++i) { w1x[i] = W1[i*HID + j]; w1y[i] = W1[i*HID + j + 64]; }
    const float b1x = b1[j], b1y = b1[j + 64];

    // W2 stored in z1-slot order so LDS reads are linear float4s
    float w2x[128], w2y[128];
#pragma unroll
    for (int q = 0; q < 64; ++q) {
        w2x[2*q]   = W2[q*HID + j];
        w2y[2*q]   = W2[q*HID + j + 64];
        w2x[2*q+1] = W2[(q+64)*HID + j];
        w2y[2*q+1] = W2[(q+64)*HID + j + 64];
    }
    const float b2x = b2[j], b2y = b2[j + 64];

    // W3: this lane accumulates drift[m] over z2 slots [half*64, half*64+64)
    float w3r[64];
#pragma unroll
    for (int i = 0; i < 64; ++i) {
        const int s    = half*64 + i;
        const int unit = (s >> 1) + (s & 1)*64;   // slot -> hidden unit
        w3r[i] = W3[unit*HD + m];
    }
    const float b3r = b3[m];

    // heads: lower half owns d, upper half owns t; c computed in both (redundant)
    const float whr = (half == 0) ? Wd[m] : Wt[m];
    const float wcr = Wc[m];
    const float bd0 = bd[0], bt0 = bt[0], bc0 = bc[0];

    float hm   = h0[m];   // h[m], replicated in both halves
    float xm   = hm;      // current stage input state x[m]
    float kacc = 0.0f;

    const float DT  = 5.0f / 60.0f;
    const float HDT = 0.5f * DT;
    const float W6  = DT / 6.0f;

    // u double-buffer (broadcast loads, L2-cached)
    float4 ua = *(const float4*)(U);
    float4 ub = *(const float4*)(U + 4);

    xbuf[m] = xm;                       // both halves write same value: benign
    __builtin_amdgcn_wave_barrier();

    for (int t = 0; t < T_STEPS; ++t) {
        const int tn = (t + 1 < T_STEPS) ? (t + 1) : t;
        const float4 na = *(const float4*)(U + tn * 8);
        const float4 nb = *(const float4*)(U + tn * 8 + 4);

        // ---- heads from current h (pre-update), pure register + shuffle ----
        {
            float p  = hm * whr;   // lower: d-partial, upper: t-partial
            float pc = hm * wcr;
            p += __shfl_xor(p, 16);  pc += __shfl_xor(pc, 16);
            p += __shfl_xor(p, 8);   pc += __shfl_xor(pc, 8);
            p += __shfl_xor(p, 4);   pc += __shfl_xor(pc, 4);
            p += __shfl_xor(p, 2);   pc += __shfl_xor(pc, 2);
            p += __shfl_xor(p, 1);   pc += __shfl_xor(pc, 1);
            if (tid == 0)  { out[t] = p + bd0; out[2*T_STEPS + t] = pc + bc0; }
            if (tid == 32) { out[T_STEPS + t] = p + bt0; }
        }

        // ---- u-projection: constant across the 4 RK stages, hoisted ----
        float upx = b1x, upy = b1y;
        {
            upx = fmaf(ua.x, w1x[32], upx);  upy = fmaf(ua.x, w1y[32], upy);
            upx = fmaf(ua.y, w1x[33], upx);  upy = fmaf(ua.y, w1y[33], upy);
            upx = fmaf(ua.z, w1x[34], upx);  upy = fmaf(ua.z, w1y[34], upy);
            upx = fmaf(ua.w, w1x[35], upx);  upy = fmaf(ua.w, w1y[35], upy);
            upx = fmaf(ub.x, w1x[36], upx);  upy = fmaf(ub.x, w1y[36], upy);
            upx = fmaf(ub.y, w1x[37], upx);  upy = fmaf(ub.y, w1y[37], upy);
            upx = fmaf(ub.z, w1x[38], upx);  upy = fmaf(ub.z, w1y[38], upy);
            upx = fmaf(ub.w, w1x[39], upx);  upy = fmaf(ub.w, w1y[39], upy);
        }

#pragma unroll
        for (int st = 0; st < 4; ++st) {
            // ---- L1: z1 = silu([x,u] @ W1 + b1), two outputs per lane ----
            float a0a = upx, a0b = 0.0f, a1a = upy, a1b = 0.0f;
            const float4* xv = (const float4*)xbuf;
#pragma unroll
            for (int i4 = 0; i4 < 8; ++i4) {
                const float4 v = xv[i4];   // broadcast read, conflict-free
                a0a = fmaf(v.x, w1x[4*i4+0], a0a);  a1a = fmaf(v.x, w1y[4*i4+0], a1a);
                a0b = fmaf(v.y, w1x[4*i4+1], a0b);  a1b = fmaf(v.y, w1y[4*i4+1], a1b);
                a0a = fmaf(v.z, w1x[4*i4+2], a0a);  a1a = fmaf(v.z, w1y[4*i4+2], a1a);
                a0b = fmaf(v.w, w1x[4*i4+3], a0b);  a1b = fmaf(v.w, w1y[4*i4+3], a1b);
            }
            const float z1x = silu_f(a0a + a0b);
            const float z1y = silu_f(a1a + a1b);
            *(float2*)&z1buf[2*j] = make_float2(z1x, z1y);   // one ds_write_b64
            __builtin_amdgcn_wave_barrier();                 // order write < reads

            // ---- L2: z2 = silu(z1 @ W2 + b2), two outputs per lane ----
            float c0a = b2x, c0b = 0.0f, c1a = b2y, c1b = 0.0f;
            const float4* z1v = (const float4*)z1buf;
#pragma unroll
            for (int i4 = 0; i4 < 32; ++i4) {
                const float4 v = z1v[i4];  // broadcast read
                c0a = fmaf(v.x, w2x[4*i4+0], c0a);  c1a = fmaf(v.x, w2y[4*i4+0], c1a);
                c0b = fmaf(v.y, w2x[4*i4+1], c0b);  c1b = fmaf(v.y, w2y[4*i4+1], c1b);
                c0a = fmaf(v.z, w2x[4*i4+2], c0a);  c1a = fmaf(v.z, w2y[4*i4+2], c1a);
                c0b = fmaf(v.w, w2x[4*i4+3], c0b);  c1b = fmaf(v.w, w2y[4*i4+3], c1b);
            }
            const float z2x = silu_f(c0a + c0b);
            const float z2y = silu_f(c1a + c1b);
            *(float2*)&z2buf[2*j] = make_float2(z2x, z2y);
            __builtin_amdgcn_wave_barrier();

            // ---- L3: drift[m] partial over this half's 64 z2 slots ----
            float p0 = 0.0f, p1 = 0.0f, p2 = 0.0f, p3 = 0.0f;
            const float4* z2v = (const float4*)(z2buf + half*64);
#pragma unroll
            for (int i4 = 0; i4 < 16; ++i4) {
                const float4 v = z2v[i4];  // 2 addr groups across wave: free
                p0 = fmaf(v.x, w3r[4*i4+0], p0);
                p1 = fmaf(v.y, w3r[4*i4+1], p1);
                p2 = fmaf(v.z, w3r[4*i4+2], p2);
                p3 = fmaf(v.w, w3r[4*i4+3], p3);
            }
            float drift = (p0 + p1) + (p2 + p3);
            drift += __shfl_xor(drift, 32);   // combine the two K-halves
            drift += b3r;

            // ---- RK combine (computed redundantly in both halves) ----
            const float k = 0.02f * drift - 0.1f * xm;
            if (st == 0)      { kacc = k;           xm = hm + HDT * k; }
            else if (st == 1) { kacc += 2.0f * k;   xm = hm + HDT * k; }
            else if (st == 2) { kacc += 2.0f * k;   xm = hm + DT  * k; }
            else {
                kacc += k;
                float hn = hm + W6 * kacc;
                if (!isfinite(hn)) hn = 0.0f;        // nan_to_num BEFORE tanh
                hn = tanhf(hn);
                hn = fminf(fmaxf(hn, -5.0f), 5.0f);  // fidelity no-op after tanh
                hm = hn; xm = hn;
            }
            xbuf[m] = xm;                     // both halves write same value
            __builtin_amdgcn_wave_barrier();
        }
        ua = na; ub = nb;
    }

    if (tid < 32) out[3*T_STEPS + tid] = hm;
}

extern "C" void kernel_launch(void* const* d_in, const int* in_sizes, int n_in,
                              void* d_out, int out_size, void* d_ws, size_t ws_size,
                              hipStream_t stream) {
    const float* U  = (const float*)d_in[0];
    const float* h0 = (const float*)d_in[1];
    const float* W1 = (const float*)d_in[2];
    const float* b1 = (const float*)d_in[3];
    const float* W2 = (const float*)d_in[4];
    const float* b2 = (const float*)d_in[5];
    const float* W3 = (const float*)d_in[6];
    const float* b3 = (const float*)d_in[7];
    const float* Wd = (const float*)d_in[8];
    const float* bd = (const float*)d_in[9];
    const float* Wt = (const float*)d_in[10];
    const float* bt = (const float*)d_in[11];
    const float* Wc = (const float*)d_in[12];
    const float* bc = (const float*)d_in[13];
    float* out = (float*)d_out;

    node_scan<<<1, 64, 0, stream>>>(U, h0, W1, b1, W2, b2, W3, b3,
                                    Wd, bd, Wt, bt, Wc, bc, out);
}

// Round 3
// 408880.957 us; speedup vs baseline: 3.8362x; 3.8362x over previous
//
#include <hip/hip_runtime.h>
#include <math.h>

// ControlledNODE: sequential RK4 scan, T=65536 steps.
// SINGLE-WAVE (64 threads = 1 wave), barrier-free: DS ops of one wave
// execute in program order; __builtin_amdgcn_wave_barrier() is a free
// compile-time ordering fence. Round-2 lesson: 400 weight floats/lane
// spilled to scratch (arch-VGPR cap is 256). Fix: W2 lives ONCE in LDS
// (64 KB, paired-slot layout, conflict-free ds_read_b128); W1+W3 stay
// in VGPRs (~144). Total regs ~210 -> no spill.

constexpr int T_STEPS = 65536;
constexpr int HD  = 32;   // state dim
constexpr int HID = 128;  // hidden dim

__device__ __forceinline__ float silu_f(float a) {
    // a * sigmoid(a); exp overflow -> inf -> a/inf = 0 (correct limit)
    return a / (1.0f + __expf(-a));
}

__global__ __launch_bounds__(64, 1)
void node_scan(const float* __restrict__ U,
               const float* __restrict__ h0,
               const float* __restrict__ W1, const float* __restrict__ b1,
               const float* __restrict__ W2, const float* __restrict__ b2,
               const float* __restrict__ W3, const float* __restrict__ b3,
               const float* __restrict__ Wd, const float* __restrict__ bd,
               const float* __restrict__ Wt, const float* __restrict__ bt,
               const float* __restrict__ Wc, const float* __restrict__ bc,
               float* __restrict__ out)
{
    const int tid  = threadIdx.x;   // 0..63
    const int j    = tid;           // owns hidden units j and j+64
    const int m    = tid & 31;      // drift/state index
    const int half = tid >> 5;      // 0 or 1: L3 K-half, head selector

    // W2 in paired-slot layout: row r (r=0..63) covers z1 slots 2r,2r+1.
    // w2l[r*256 + 4*jj + {0,1,2,3}] = { W2[r][jj], W2[r][jj+64],
    //                                   W2[r+64][jj], W2[r+64][jj+64] }
    __shared__ __align__(16) float w2l[64 * 256];   // 64 KB
    __shared__ __align__(16) float xbuf[HD];        // current RK-stage state
    __shared__ __align__(16) float z1buf[HID];      // slot 2q = unit q, 2q+1 = unit q+64
    __shared__ __align__(16) float z2buf[HID];      // same slot layout

    // ---- one-time: stage W2 into LDS (coalesced per row) ----
    for (int r = 0; r < 64; ++r) {
        float4 v;
        v.x = W2[r*HID + tid];
        v.y = W2[r*HID + tid + 64];
        v.z = W2[(r+64)*HID + tid];
        v.w = W2[(r+64)*HID + tid + 64];
        *(float4*)&w2l[r*256 + 4*tid] = v;
    }

    // ---- one-time: small weights into registers ----
    float w1x[40], w1y[40];
#pragma unroll
    for (int i = 0; i < 40; ++i) { w1x[i] = W1[i*HID + j]; w1y[i] = W1[i*HID + j + 64]; }
    const float b1x = b1[j], b1y = b1[j + 64];
    const float b2x = b2[j], b2y = b2[j + 64];

    // W3: this lane accumulates drift[m] over z2 slots [half*64, half*64+64)
    float w3r[64];
#pragma unroll
    for (int i = 0; i < 64; ++i) {
        const int s    = half*64 + i;
        const int unit = (s >> 1) + (s & 1)*64;   // slot -> hidden unit
        w3r[i] = W3[unit*HD + m];
    }
    const float b3r = b3[m];

    // heads: lower half owns d, upper half owns t; c computed in both (redundant)
    const float whr = (half == 0) ? Wd[m] : Wt[m];
    const float wcr = Wc[m];
    const float bd0 = bd[0], bt0 = bt[0], bc0 = bc[0];

    float hm   = h0[m];   // h[m], replicated in both halves
    float xm   = hm;      // current stage input state x[m]
    float kacc = 0.0f;

    const float DT  = 5.0f / 60.0f;
    const float HDT = 0.5f * DT;
    const float W6  = DT / 6.0f;

    // u double-buffer (broadcast loads, L2-cached)
    float4 ua = *(const float4*)(U);
    float4 ub = *(const float4*)(U + 4);

    xbuf[m] = xm;                       // both halves write same value: benign
    __builtin_amdgcn_wave_barrier();

    const float4* wp = (const float4*)w2l + j;   // lane base; row stride = 64 float4

    for (int t = 0; t < T_STEPS; ++t) {
        const int tn = (t + 1 < T_STEPS) ? (t + 1) : t;
        const float4 na = *(const float4*)(U + tn * 8);
        const float4 nb = *(const float4*)(U + tn * 8 + 4);

        // ---- heads from current h (pre-update), pure register + shuffle ----
        {
            float p  = hm * whr;   // lower: d-partial, upper: t-partial
            float pc = hm * wcr;
            p += __shfl_xor(p, 16);  pc += __shfl_xor(pc, 16);
            p += __shfl_xor(p, 8);   pc += __shfl_xor(pc, 8);
            p += __shfl_xor(p, 4);   pc += __shfl_xor(pc, 4);
            p += __shfl_xor(p, 2);   pc += __shfl_xor(pc, 2);
            p += __shfl_xor(p, 1);   pc += __shfl_xor(pc, 1);
            if (tid == 0)  { out[t] = p + bd0; out[2*T_STEPS + t] = pc + bc0; }
            if (tid == 32) { out[T_STEPS + t] = p + bt0; }
        }

        // ---- u-projection: constant across the 4 RK stages, hoisted ----
        float upx = b1x, upy = b1y;
        upx = fmaf(ua.x, w1x[32], upx);  upy = fmaf(ua.x, w1y[32], upy);
        upx = fmaf(ua.y, w1x[33], upx);  upy = fmaf(ua.y, w1y[33], upy);
        upx = fmaf(ua.z, w1x[34], upx);  upy = fmaf(ua.z, w1y[34], upy);
        upx = fmaf(ua.w, w1x[35], upx);  upy = fmaf(ua.w, w1y[35], upy);
        upx = fmaf(ub.x, w1x[36], upx);  upy = fmaf(ub.x, w1y[36], upy);
        upx = fmaf(ub.y, w1x[37], upx);  upy = fmaf(ub.y, w1y[37], upy);
        upx = fmaf(ub.z, w1x[38], upx);  upy = fmaf(ub.z, w1y[38], upy);
        upx = fmaf(ub.w, w1x[39], upx);  upy = fmaf(ub.w, w1y[39], upy);

#pragma unroll
        for (int st = 0; st < 4; ++st) {
            // ---- L1: z1 = silu([x,u] @ W1 + b1), two outputs per lane ----
            float a0a = upx, a0b = 0.0f, a1a = upy, a1b = 0.0f;
            const float4* xv = (const float4*)xbuf;
#pragma unroll
            for (int i4 = 0; i4 < 8; ++i4) {
                const float4 v = xv[i4];   // broadcast read, conflict-free
                a0a = fmaf(v.x, w1x[4*i4+0], a0a);  a1a = fmaf(v.x, w1y[4*i4+0], a1a);
                a0b = fmaf(v.y, w1x[4*i4+1], a0b);  a1b = fmaf(v.y, w1y[4*i4+1], a1b);
                a0a = fmaf(v.z, w1x[4*i4+2], a0a);  a1a = fmaf(v.z, w1y[4*i4+2], a1a);
                a0b = fmaf(v.w, w1x[4*i4+3], a0b);  a1b = fmaf(v.w, w1y[4*i4+3], a1b);
            }
            const float z1x = silu_f(a0a + a0b);
            const float z1y = silu_f(a1a + a1b);
            *(float2*)&z1buf[2*j] = make_float2(z1x, z1y);   // one ds_write_b64
            __builtin_amdgcn_wave_barrier();                 // order write < reads

            // ---- L2: z2 = silu(z1 @ W2 + b2); W2 from LDS, z1 broadcast ----
            float c0a = b2x, c0b = 0.0f, c1a = b2y, c1b = 0.0f;
            const float4* z1v = (const float4*)z1buf;
#pragma unroll
            for (int rr = 0; rr < 32; ++rr) {
                const float4 zq = z1v[rr];            // z1 slots 4rr..4rr+3 (broadcast)
                const float4 wa = wp[(2*rr    )*64];  // pair-row 2rr   (imm offset)
                const float4 wb = wp[(2*rr + 1)*64];  // pair-row 2rr+1 (imm offset)
                c0a = fmaf(zq.x, wa.x, c0a);  c1a = fmaf(zq.x, wa.y, c1a);
                c0b = fmaf(zq.y, wa.z, c0b);  c1b = fmaf(zq.y, wa.w, c1b);
                c0a = fmaf(zq.z, wb.x, c0a);  c1a = fmaf(zq.z, wb.y, c1a);
                c0b = fmaf(zq.w, wb.z, c0b);  c1b = fmaf(zq.w, wb.w, c1b);
            }
            const float z2x = silu_f(c0a + c0b);
            const float z2y = silu_f(c1a + c1b);
            *(float2*)&z2buf[2*j] = make_float2(z2x, z2y);
            __builtin_amdgcn_wave_barrier();

            // ---- L3: drift[m] partial over this half's 64 z2 slots ----
            float p0 = 0.0f, p1 = 0.0f, p2 = 0.0f, p3 = 0.0f;
            const float4* z2v = (const float4*)(z2buf + half*64);
#pragma unroll
            for (int i4 = 0; i4 < 16; ++i4) {
                const float4 v = z2v[i4];  // 2 addr groups across wave: free
                p0 = fmaf(v.x, w3r[4*i4+0], p0);
                p1 = fmaf(v.y, w3r[4*i4+1], p1);
                p2 = fmaf(v.z, w3r[4*i4+2], p2);
                p3 = fmaf(v.w, w3r[4*i4+3], p3);
            }
            float drift = (p0 + p1) + (p2 + p3);
            drift += __shfl_xor(drift, 32);   // combine the two K-halves
            drift += b3r;

            // ---- RK combine (computed redundantly in both halves) ----
            const float k = 0.02f * drift - 0.1f * xm;
            if (st == 0)      { kacc = k;           xm = hm + HDT * k; }
            else if (st == 1) { kacc += 2.0f * k;   xm = hm + HDT * k; }
            else if (st == 2) { kacc += 2.0f * k;   xm = hm + DT  * k; }
            else {
                kacc += k;
                float hn = hm + W6 * kacc;
                if (!isfinite(hn)) hn = 0.0f;        // nan_to_num BEFORE tanh
                hn = tanhf(hn);
                hn = fminf(fmaxf(hn, -5.0f), 5.0f);  // fidelity no-op after tanh
                hm = hn; xm = hn;
            }
            xbuf[m] = xm;                     // both halves write same value
            __builtin_amdgcn_wave_barrier();
        }
        ua = na; ub = nb;
    }

    if (tid < 32) out[3*T_STEPS + tid] = hm;
}

extern "C" void kernel_launch(void* const* d_in, const int* in_sizes, int n_in,
                              void* d_out, int out_size, void* d_ws, size_t ws_size,
                              hipStream_t stream) {
    const float* U  = (const float*)d_in[0];
    const float* h0 = (const float*)d_in[1];
    const float* W1 = (const float*)d_in[2];
    const float* b1 = (const float*)d_in[3];
    const float* W2 = (const float*)d_in[4];
    const float* b2 = (const float*)d_in[5];
    const float* W3 = (const float*)d_in[6];
    const float* b3 = (const float*)d_in[7];
    const float* Wd = (const float*)d_in[8];
    const float* bd = (const float*)d_in[9];
    const float* Wt = (const float*)d_in[10];
    const float* bt = (const float*)d_in[11];
    const float* Wc = (const float*)d_in[12];
    const float* bc = (const float*)d_in[13];
    float* out = (float*)d_out;

    node_scan<<<1, 64, 0, stream>>>(U, h0, W1, b1, W2, b2, W3, b3,
                                    Wd, bd, Wt, bt, Wc, bc, out);
}

// Round 4
// 333040.479 us; speedup vs baseline: 4.7097x; 1.2277x over previous
//
#include <hip/hip_runtime.h>
#include <math.h>

// ControlledNODE: sequential RK4 scan, T=65536 steps.
// Round-4 design: 128 threads = 2 waves on one CU.
//  * W1/W2/W3 columns fully register-resident (~200 floats/lane, fits
//    256 arch VGPRs; round-2 showed ~456 spills, round-3 showed single
//    wave can't hide its own LDS latency).
//  * Raw barriers: s_waitcnt lgkmcnt(0) + s_barrier -- NO vmcnt(0) drain
//    (unlike __syncthreads), so U-prefetch/out-stores ride across.
//  * RK combine computed redundantly in ALL lanes from pbuf, so hm is
//    replicated everywhere: heads are pure reg+shuffle, no extra barrier.
// 4 barriers per RK stage, 16 per step.

constexpr int T_STEPS = 65536;
constexpr int HD  = 32;   // state dim
constexpr int HID = 128;  // hidden dim

__device__ __forceinline__ float silu_f(float a) {
    // a * sigmoid(a); exp overflow -> inf -> a/inf = 0 (correct limit)
    return a / (1.0f + __expf(-a));
}

// Workgroup barrier without vmcnt drain: LDS writes complete (lgkmcnt),
// then s_barrier. asm "memory" clobbers fence compiler reordering of DS
// ops across the barrier in both directions.
__device__ __forceinline__ void wg_barrier() {
    asm volatile("s_waitcnt lgkmcnt(0)" ::: "memory");
    __builtin_amdgcn_s_barrier();
    asm volatile("" ::: "memory");
}

__global__ __launch_bounds__(128, 1)
void node_scan(const float* __restrict__ U,
               const float* __restrict__ h0,
               const float* __restrict__ W1, const float* __restrict__ b1,
               const float* __restrict__ W2, const float* __restrict__ b2,
               const float* __restrict__ W3, const float* __restrict__ b3,
               const float* __restrict__ Wd, const float* __restrict__ bd,
               const float* __restrict__ Wt, const float* __restrict__ bt,
               const float* __restrict__ Wc, const float* __restrict__ bc,
               float* __restrict__ out)
{
    const int tid = threadIdx.x;    // 0..127
    const int j   = tid;            // hidden unit owned (L1/L2)
    const int m   = tid & 31;       // state/drift index
    const int seg = tid >> 5;       // L3 K-segment 0..3
    const int wl  = tid & 63;       // lane within wave
    const int wv  = tid >> 6;       // wave id 0/1

    __shared__ __align__(16) float xbuf[HD];     // RK-stage state input
    __shared__ __align__(16) float z1buf[HID];
    __shared__ __align__(16) float z2buf[HID];
    __shared__ __align__(16) float pbuf[HID];    // L3 partials

    // ---- one-time: weights into registers (all constant-indexed) ----
    float w1r[40];
#pragma unroll
    for (int i = 0; i < 40; ++i) w1r[i] = W1[i * HID + j];
    const float b1r = b1[j];

    float w2r[HID];
#pragma unroll
    for (int i = 0; i < HID; ++i) w2r[i] = W2[i * HID + j];
    const float b2r = b2[j];

    float w3r[32];
#pragma unroll
    for (int i = 0; i < 32; ++i) w3r[i] = W3[(seg * 32 + i) * HD + m];
    const float b3r = b3[m];

    // heads: wave0 reduces d (and c), wave1 reduces t (c duplicate unused)
    const float whr = (wv == 0) ? Wd[m] : Wt[m];
    const float wcr = Wc[m];
    const float bd0 = bd[0], bt0 = bt[0], bc0 = bc[0];

    float hm   = h0[m];    // replicated in all 128 lanes
    float xm   = hm;       // current stage input state x[m]
    float kacc = 0.0f;

    const float DT  = 5.0f / 60.0f;
    const float HDT = 0.5f * DT;
    const float W6  = DT / 6.0f;

    // u double-buffer (same addr all lanes -> broadcast, L2-cached)
    float4 ua = *(const float4*)(U);
    float4 ub = *(const float4*)(U + 4);

    if (tid < HD) xbuf[tid] = xm;
    wg_barrier();

    for (int t = 0; t < T_STEPS; ++t) {
        // prefetch next step's u (never drained by barriers: no vmcnt wait)
        const int tn = (t + 1 < T_STEPS) ? (t + 1) : t;
        const float4 na = *(const float4*)(U + tn * 8);
        const float4 nb = *(const float4*)(U + tn * 8 + 4);

        // ---- heads from current h (pre-update): pure reg + shuffle ----
        {
            float p  = (wl < 32) ? hm * whr : 0.0f;
            float pc = (wl < 32) ? hm * wcr : 0.0f;
            p += __shfl_xor(p, 32);  pc += __shfl_xor(pc, 32);
            p += __shfl_xor(p, 16);  pc += __shfl_xor(pc, 16);
            p += __shfl_xor(p, 8);   pc += __shfl_xor(pc, 8);
            p += __shfl_xor(p, 4);   pc += __shfl_xor(pc, 4);
            p += __shfl_xor(p, 2);   pc += __shfl_xor(pc, 2);
            p += __shfl_xor(p, 1);   pc += __shfl_xor(pc, 1);
            if (tid == 0)  { out[t] = p + bd0; out[2 * T_STEPS + t] = pc + bc0; }
            if (tid == 64) { out[T_STEPS + t] = p + bt0; }
        }

        // ---- u-projection: constant across the 4 RK stages, hoisted ----
        float upj = b1r;
        upj = fmaf(ua.x, w1r[32], upj);
        upj = fmaf(ua.y, w1r[33], upj);
        upj = fmaf(ua.z, w1r[34], upj);
        upj = fmaf(ua.w, w1r[35], upj);
        upj = fmaf(ub.x, w1r[36], upj);
        upj = fmaf(ub.y, w1r[37], upj);
        upj = fmaf(ub.z, w1r[38], upj);
        upj = fmaf(ub.w, w1r[39], upj);

#pragma unroll
        for (int st = 0; st < 4; ++st) {
            // ---- L1: z1[j] = silu([x,u] @ W1 + b1) ----
            float a0 = upj, a1 = 0.0f, a2 = 0.0f, a3 = 0.0f;
            const float4* xv = (const float4*)xbuf;
#pragma unroll
            for (int i4 = 0; i4 < 8; ++i4) {
                const float4 v = xv[i4];            // broadcast read
                a0 = fmaf(v.x, w1r[4 * i4 + 0], a0);
                a1 = fmaf(v.y, w1r[4 * i4 + 1], a1);
                a2 = fmaf(v.z, w1r[4 * i4 + 2], a2);
                a3 = fmaf(v.w, w1r[4 * i4 + 3], a3);
            }
            z1buf[j] = silu_f((a0 + a1) + (a2 + a3));
            wg_barrier();                            // B1

            // ---- L2: z2[j] = silu(z1 @ W2 + b2), W2 in registers ----
            float c0 = b2r, c1 = 0.0f, c2 = 0.0f, c3 = 0.0f;
            const float4* z1v = (const float4*)z1buf;
#pragma unroll
            for (int i4 = 0; i4 < 32; ++i4) {
                const float4 v = z1v[i4];           // broadcast read
                c0 = fmaf(v.x, w2r[4 * i4 + 0], c0);
                c1 = fmaf(v.y, w2r[4 * i4 + 1], c1);
                c2 = fmaf(v.z, w2r[4 * i4 + 2], c2);
                c3 = fmaf(v.w, w2r[4 * i4 + 3], c3);
            }
            z2buf[j] = silu_f((c0 + c1) + (c2 + c3));
            wg_barrier();                            // B2

            // ---- L3 partial: drift[m] over segment seg ----
            float p0 = 0.0f, p1 = 0.0f, p2 = 0.0f, p3 = 0.0f;
            const float4* z2v = (const float4*)(z2buf + seg * 32);
#pragma unroll
            for (int i4 = 0; i4 < 8; ++i4) {
                const float4 v = z2v[i4];           // 2 addr groups: free
                p0 = fmaf(v.x, w3r[4 * i4 + 0], p0);
                p1 = fmaf(v.y, w3r[4 * i4 + 1], p1);
                p2 = fmaf(v.z, w3r[4 * i4 + 2], p2);
                p3 = fmaf(v.w, w3r[4 * i4 + 3], p3);
            }
            pbuf[tid] = (p0 + p1) + (p2 + p3);
            wg_barrier();                            // B3

            // ---- RK combine: ALL lanes redundantly (hm replicated) ----
            {
                const float drift = ((pbuf[m] + pbuf[m + 32]) +
                                     (pbuf[m + 64] + pbuf[m + 96])) + b3r;
                const float k = 0.02f * drift - 0.1f * xm;
                if (st == 0)      { kacc = k;           xm = hm + HDT * k; }
                else if (st == 1) { kacc += 2.0f * k;   xm = hm + HDT * k; }
                else if (st == 2) { kacc += 2.0f * k;   xm = hm + DT  * k; }
                else {
                    kacc += k;
                    float hn = hm + W6 * kacc;
                    if (!isfinite(hn)) hn = 0.0f;        // nan_to_num BEFORE tanh
                    hn = tanhf(hn);
                    hn = fminf(fmaxf(hn, -5.0f), 5.0f);  // fidelity no-op after tanh
                    hm = hn; xm = hn;
                }
                if (tid < HD) xbuf[tid] = xm;
            }
            wg_barrier();                            // B4
        }
        ua = na; ub = nb;
    }

    if (tid < HD) out[3 * T_STEPS + tid] = hm;
}

extern "C" void kernel_launch(void* const* d_in, const int* in_sizes, int n_in,
                              void* d_out, int out_size, void* d_ws, size_t ws_size,
                              hipStream_t stream) {
    const float* U  = (const float*)d_in[0];
    const float* h0 = (const float*)d_in[1];
    const float* W1 = (const float*)d_in[2];
    const float* b1 = (const float*)d_in[3];
    const float* W2 = (const float*)d_in[4];
    const float* b2 = (const float*)d_in[5];
    const float* W3 = (const float*)d_in[6];
    const float* b3 = (const float*)d_in[7];
    const float* Wd = (const float*)d_in[8];
    const float* bd = (const float*)d_in[9];
    const float* Wt = (const float*)d_in[10];
    const float* bt = (const float*)d_in[11];
    const float* Wc = (const float*)d_in[12];
    const float* bc = (const float*)d_in[13];
    float* out = (float*)d_out;

    node_scan<<<1, 128, 0, stream>>>(U, h0, W1, b1, W2, b2, W3, b3,
                                     Wd, bd, Wt, bt, Wc, bc, out);
}